// Round 11
// baseline (188.179 us; speedup 1.0000x reference)
//
#include <hip/hip_runtime.h>
#include <stdint.h>

#define B 4
#define T 256
#define V 1024
#define S 64
#define DIM 1024
#define CV 256

typedef __attribute__((ext_vector_type(8))) short bf16x8;
typedef __attribute__((ext_vector_type(4))) short s16x4;
typedef __attribute__((ext_vector_type(4))) float f32x4;

// ---- workspace layout, 4-byte word offsets. CORRECTLY sized (R5-R10 had
// ---- WkT/WvT/XB at half size -> overlapping writes; this round fixes it). ----
enum : int {
    VUB_O  = 0,                     // [B*V][DIM] bf16: vision@Wu + bu  (8 MB)
    YB_O   = VUB_O + 2097152,       // [B*T][DIM] bf16: x@Wk^T         (2 MB)
    WVT_O  = YB_O + 524288,         // [DIM][DIM] bf16: Wv^T [d][e]    (2 MB)
    UB_O   = WVT_O + 524288,        // [B*T][DIM] bf16: sum_s p*vu_row (2 MB)
    RS_O   = UB_O + 524288,         // [B*T]   f32 per-token sum of p
    PIDX_O = RS_O + B*T,            // [B*T*S] int selected v indices
    WS_TOTAL = PIDX_O + B*T*S       // ~15 MB total
};

__device__ __forceinline__ short f2bf(float f) {
    union { float f; unsigned u; } x; x.f = f;
    unsigned r = (x.u + 0x7FFF + ((x.u >> 16) & 1)) >> 16;
    return (short)r;
}
__device__ __forceinline__ float bf2f(short s) {
    union { unsigned u; float f; } x;
    x.u = ((unsigned)(unsigned short)s) << 16;
    return x.f;
}
// load 8 consecutive f32 and round-convert to a bf16x8 fragment
__device__ __forceinline__ bf16x8 ld_cvt8(const float* __restrict__ p) {
    float4 f0 = *(const float4*)p;
    float4 f1 = *(const float4*)(p + 4);
    bf16x8 r;
    r[0] = f2bf(f0.x); r[1] = f2bf(f0.y); r[2] = f2bf(f0.z); r[3] = f2bf(f0.w);
    r[4] = f2bf(f1.x); r[5] = f2bf(f1.y); r[6] = f2bf(f1.z); r[7] = f2bf(f1.w);
    return r;
}

// ---- per-wave 32x32 MFMA tile from bf16 A[m][k] / Bt[n][k] (both k-contig) ----
template<int K, int LDA, int LDB>
__device__ __forceinline__ void wave_mma(const short* __restrict__ A0,
                                         const short* __restrict__ B0,
                                         f32x4 acc[2][2]) {
    int lane = threadIdx.x & 63;
    int rw = lane & 15, q = lane >> 4;
    const short* ap0 = A0 + rw * LDA + q * 8;
    const short* ap1 = ap0 + 16 * LDA;
    const short* bp0 = B0 + rw * LDB + q * 8;
    const short* bp1 = bp0 + 16 * LDB;
#pragma unroll 4
    for (int kc = 0; kc < K; kc += 32) {
        bf16x8 a0 = *(const bf16x8*)(ap0 + kc);
        bf16x8 a1 = *(const bf16x8*)(ap1 + kc);
        bf16x8 b0 = *(const bf16x8*)(bp0 + kc);
        bf16x8 b1 = *(const bf16x8*)(bp1 + kc);
        acc[0][0] = __builtin_amdgcn_mfma_f32_16x16x32_bf16(a0, b0, acc[0][0], 0, 0, 0);
        acc[0][1] = __builtin_amdgcn_mfma_f32_16x16x32_bf16(a0, b1, acc[0][1], 0, 0, 0);
        acc[1][0] = __builtin_amdgcn_mfma_f32_16x16x32_bf16(a1, b0, acc[1][0], 0, 0, 0);
        acc[1][1] = __builtin_amdgcn_mfma_f32_16x16x32_bf16(a1, b1, acc[1][1], 0, 0, 0);
    }
}

// ================= k1: ALL depth-0/1 work in one dispatch =====================
// blocks [0,1024)    : VU'[v,e] = vision @ Wu + bu  (LDS-transposed Wu, 64x64)
// blocks [1024,1280) : Y[bt,e]  = x @ Wk^T          (both natural f32, 64x64)
// blocks [1280,1536) : Wv transpose-convert -> WVT bf16 [d][e]
// blocks [1536,1600) : mask compaction (self-detecting encoding)
__global__ void k1(const float* __restrict__ vision, const float* __restrict__ Wu,
                   const float* __restrict__ bu, const float* __restrict__ x,
                   const float* __restrict__ Wk, const float* __restrict__ Wv,
                   const void* __restrict__ maskp,
                   float* __restrict__ ws, int* __restrict__ wsi) {
    __shared__ short smem[64 * 264];            // 33 KB, aliased per block role
    int blk = blockIdx.x, tid = threadIdx.x;
    int lane = tid & 63, wvi = tid >> 6;
    int rw = lane & 15, q = lane >> 4;

    if (blk < 1024) {
        // ---- VU' GEMM: m = flat (b,v) row in [0,4096), n = e in [0,1024), K=256
        int m0 = (blk >> 4) * 64, n0 = (blk & 15) * 64;
        // stage Wu[cv][n0..n0+64) transposed -> smem bf16 [e-local 64][264]
#pragma unroll
        for (int p = 0; p < 16; p++) {
            int f4 = p * 256 + tid;               // 4096 float4 of the 256x64 tile
            int cv = f4 >> 4, c4 = (f4 & 15) * 4;
            float4 w = ((const float4*)(Wu + (size_t)cv * DIM + n0))[f4 & 15];
            smem[(c4 + 0) * 264 + cv] = f2bf(w.x);
            smem[(c4 + 1) * 264 + cv] = f2bf(w.y);
            smem[(c4 + 2) * 264 + cv] = f2bf(w.z);
            smem[(c4 + 3) * 264 + cv] = f2bf(w.w);
        }
        __syncthreads();
        int wm = (wvi >> 1) * 32, wn = (wvi & 1) * 32;
        const float* a0p = vision + (size_t)(m0 + wm + rw) * CV + q * 8;
        const float* a1p = a0p + 16 * CV;
        const short* b0p = smem + (wn + rw) * 264 + q * 8;
        const short* b1p = b0p + 16 * 264;
        f32x4 acc[2][2] = {};
#pragma unroll
        for (int kc = 0; kc < CV; kc += 32) {
            bf16x8 a0 = ld_cvt8(a0p + kc);
            bf16x8 a1 = ld_cvt8(a1p + kc);
            bf16x8 b0 = *(const bf16x8*)(b0p + kc);
            bf16x8 b1 = *(const bf16x8*)(b1p + kc);
            acc[0][0] = __builtin_amdgcn_mfma_f32_16x16x32_bf16(a0, b0, acc[0][0], 0, 0, 0);
            acc[0][1] = __builtin_amdgcn_mfma_f32_16x16x32_bf16(a0, b1, acc[0][1], 0, 0, 0);
            acc[1][0] = __builtin_amdgcn_mfma_f32_16x16x32_bf16(a1, b0, acc[1][0], 0, 0, 0);
            acc[1][1] = __builtin_amdgcn_mfma_f32_16x16x32_bf16(a1, b1, acc[1][1], 0, 0, 0);
        }
        int col = lane & 15;
        short* vub = (short*)(ws + VUB_O);
        float bu0 = bu[n0 + wn + col], bu1 = bu[n0 + wn + 16 + col];
#pragma unroll
        for (int i = 0; i < 2; i++)
#pragma unroll
            for (int j = 0; j < 2; j++) {
                float badd = j ? bu1 : bu0;
#pragma unroll
                for (int r = 0; r < 4; r++) {
                    int vr = m0 + wm + i * 16 + q * 4 + r;
                    int e  = n0 + wn + j * 16 + col;
                    vub[(size_t)vr * DIM + e] = f2bf(acc[i][j][r] + badd);
                }
            }
        return;
    }
    if (blk < 1280) {
        // ---- Y GEMM: m = bt in [0,1024), n = e, K=1024; f32 direct + inline cvt
        int b2 = blk - 1024;
        int m0 = (b2 >> 4) * 64, n0 = (b2 & 15) * 64;
        int wm = (wvi >> 1) * 32, wn = (wvi & 1) * 32;
        const float* a0p = x + (size_t)(m0 + wm + rw) * DIM + q * 8;
        const float* a1p = a0p + 16 * DIM;
        const float* b0p = Wk + (size_t)(n0 + wn + rw) * DIM + q * 8;
        const float* b1p = b0p + 16 * DIM;
        f32x4 acc[2][2] = {};
#pragma unroll 4
        for (int kc = 0; kc < DIM; kc += 32) {
            bf16x8 a0 = ld_cvt8(a0p + kc);
            bf16x8 a1 = ld_cvt8(a1p + kc);
            bf16x8 b0 = ld_cvt8(b0p + kc);
            bf16x8 b1 = ld_cvt8(b1p + kc);
            acc[0][0] = __builtin_amdgcn_mfma_f32_16x16x32_bf16(a0, b0, acc[0][0], 0, 0, 0);
            acc[0][1] = __builtin_amdgcn_mfma_f32_16x16x32_bf16(a0, b1, acc[0][1], 0, 0, 0);
            acc[1][0] = __builtin_amdgcn_mfma_f32_16x16x32_bf16(a1, b0, acc[1][0], 0, 0, 0);
            acc[1][1] = __builtin_amdgcn_mfma_f32_16x16x32_bf16(a1, b1, acc[1][1], 0, 0, 0);
        }
        int col = lane & 15;
        short* yb = (short*)(ws + YB_O);
#pragma unroll
        for (int i = 0; i < 2; i++)
#pragma unroll
            for (int j = 0; j < 2; j++)
#pragma unroll
                for (int r = 0; r < 4; r++)
                    yb[(size_t)(m0 + wm + i * 16 + q * 4 + r) * DIM +
                       n0 + wn + j * 16 + col] = f2bf(acc[i][j][r]);
        return;
    }
    if (blk < 1536) {
        // ---- Wv transpose-convert: [e][d] f32 -> [d][e] bf16 via LDS tile ----
        int t2 = blk - 1280;
        int e0 = (t2 >> 4) * 64, d0 = (t2 & 15) * 64;
        short* tl = smem;   // [64][65]
        short* dst = (short*)(ws + WVT_O);
        int j = tid & 63, i0 = tid >> 6;
#pragma unroll
        for (int p = 0; p < 16; p++) {
            int i = p * 4 + i0;
            tl[j * 65 + i] = f2bf(Wv[(size_t)(e0 + i) * DIM + d0 + j]);
        }
        __syncthreads();
#pragma unroll
        for (int p = 0; p < 16; p++) {
            int dd = p * 4 + i0;
            dst[(size_t)(d0 + dd) * DIM + e0 + j] = tl[dd * 65 + j];
        }
        return;
    }
    // ---- mask compaction, blocks [1536,1600): single pass, 64-bit bitmask ----
    int* si = (int*)smem;          // mc_cnt[16][17] + 2 flags
    {
        int a = 0, bfl = 0;
        const uchar4* m4 = (const uchar4*)maskp;
#pragma unroll
        for (int jj = 0; jj < 4; jj++) {
            uchar4 u = m4[tid * 4 + jj];
            if (u.y | u.z | u.w) a = 1;
            if (u.x == 0x3f || u.y == 0x3f || u.z == 0x3f || u.w == 0x3f) bfl = 1;
        }
        if (tid == 0) { si[272] = 0; si[273] = 0; }
        __syncthreads();
        if (a) si[272] = 1;        // benign same-value race
        if (bfl) si[273] = 1;
        __syncthreads();
    }
    bool byteMode = si[272] && !si[273];
    int mb = blk - 1536;
    int b = mb >> 4, tg = mb & 15;
    int tl2 = tid & 15, c = tid >> 4;
    int t = tg * 16 + tl2;
    int v0 = c * 64;
    unsigned long long bits = 0ull;
    if (byteMode) {
        const uint8_t* m = (const uint8_t*)maskp + (size_t)(b * V + v0) * T + t;
#pragma unroll 8
        for (int j = 0; j < 64; j++)
            if (m[(size_t)j * T] != 0) bits |= 1ull << j;
    } else {
        const int* m = (const int*)maskp + (size_t)(b * V + v0) * T + t;
#pragma unroll 8
        for (int j = 0; j < 64; j++)
            if (m[(size_t)j * T] != 0) bits |= 1ull << j;
    }
    si[tl2 * 17 + c] = __popcll(bits);
    __syncthreads();
    int off = 0, total = 0;
#pragma unroll
    for (int cc = 0; cc < 16; cc++) {
        int cn = si[tl2 * 17 + cc];
        if (cc < c) off += cn;
        total += cn;
    }
    int base = PIDX_O + (b * T + t) * S;
    while (bits) {
        int j = __ffsll(bits) - 1;
        bits &= bits - 1;
        if (off < S) wsi[base + off] = v0 + j;
        off++;
    }
    if (c == 15)
        for (int j = (total < S ? total : S); j < S; j++) wsi[base + j] = 0;
}

// ============== g_attn: per-bt wave — scores, exp, RS, U' accumulation ========
// score_s = VU'row_s . Y[bt]  (c0 folded into VU' via +bu);  U' = sum_s p_s VU'row
__global__ void g_attn(float* __restrict__ ws, int* __restrict__ wsi) {
    __shared__ int s_idx[4][64];
    __shared__ float s_ps[4][64];
    int tid = threadIdx.x, lane = tid & 63, wvi = tid >> 6;
    int bt = blockIdx.x * 4 + wvi, b = bt >> 8;
    s_idx[wvi][lane] = wsi[PIDX_O + bt * S + lane];   // S == 64
    int rw = lane & 15, q = lane >> 4;
    const short* vub = (const short*)(ws + VUB_O);
    const short* yp = (const short*)(ws + YB_O) + (size_t)bt * DIM + q * 8;
    f32x4 acc[4] = {};
#pragma unroll
    for (int mt = 0; mt < 4; mt++) {
        const short* ap = vub + (size_t)(b * V + s_idx[wvi][mt * 16 + rw]) * DIM + q * 8;
        f32x4 a4 = {0.f, 0.f, 0.f, 0.f};
#pragma unroll 8
        for (int kc = 0; kc < DIM; kc += 32) {
            bf16x8 av = *(const bf16x8*)(ap + kc);
            bf16x8 bv = *(const bf16x8*)(yp + kc);
            a4 = __builtin_amdgcn_mfma_f32_16x16x32_bf16(av, bv, a4, 0, 0, 0);
        }
        acc[mt] = a4;
    }
    if (rw == 0) {     // C: row = q*4+r; all 16 cols identical (Y broadcast)
#pragma unroll
        for (int mt = 0; mt < 4; mt++)
#pragma unroll
            for (int r = 0; r < 4; r++)
                s_ps[wvi][mt * 16 + q * 4 + r] = acc[mt][r];
    }
    float p = expf(s_ps[wvi][lane] * 0.03125f);   // 1/sqrt(DIM) = 1/32
    float rs = p;
    for (int o = 32; o > 0; o >>= 1) rs += __shfl_xor(rs, o);
    s_ps[wvi][lane] = p;
    if (lane == 0) ws[RS_O + bt] = rs;
    // U'[e] accum: lane covers e = jj*256 + lane*4 (+0..3), coalesced row reads
    float4 u[4] = {};
#pragma unroll 4
    for (int s = 0; s < S; s++) {
        float pv = s_ps[wvi][s];
        const short* vr = vub + (size_t)(b * V + s_idx[wvi][s]) * DIM;
#pragma unroll
        for (int jj = 0; jj < 4; jj++) {
            s16x4 r4 = *(const s16x4*)(vr + jj * 256 + lane * 4);
            u[jj].x += pv * bf2f(r4.x); u[jj].y += pv * bf2f(r4.y);
            u[jj].z += pv * bf2f(r4.z); u[jj].w += pv * bf2f(r4.w);
        }
    }
    short* ub = (short*)(ws + UB_O) + (size_t)bt * DIM;
#pragma unroll
    for (int jj = 0; jj < 4; jj++) {
        s16x4 o;
        o.x = f2bf(u[jj].x); o.y = f2bf(u[jj].y);
        o.z = f2bf(u[jj].z); o.w = f2bf(u[jj].w);
        *(s16x4*)(ub + jj * 256 + lane * 4) = o;
    }
}

// ===== g_out: out = x + (U' @ Wv)/denom; denom = sum RS of batch (no atomics) ==
__global__ void g_out_mfma(const float* __restrict__ x, float* __restrict__ ws,
                           float* __restrict__ out) {
    int w = blockIdx.x * 4 + (threadIdx.x >> 6);
    int m0 = (w >> 5) * 32, n0 = (w & 31) * 32;    // m: bt(1024), n: d(1024)
    int lane = threadIdx.x & 63;
    int b = m0 >> 8;
    float4 r4 = *(const float4*)(ws + RS_O + b * 256 + lane * 4);
    float dn = r4.x + r4.y + r4.z + r4.w;
    for (int o = 32; o > 0; o >>= 1) dn += __shfl_xor(dn, o);
    float inv = 1.0f / dn;
    const short* A = (const short*)(ws + UB_O) + (size_t)m0 * DIM;
    const short* Bt = (const short*)(ws + WVT_O) + (size_t)n0 * DIM;
    f32x4 acc[2][2] = {};
    wave_mma<DIM, DIM, DIM>(A, Bt, acc);
    int col = lane & 15, q = lane >> 4;
#pragma unroll
    for (int i = 0; i < 2; i++)
#pragma unroll
        for (int r = 0; r < 4; r++) {
            int row = m0 + i * 16 + q * 4 + r;
#pragma unroll
            for (int j = 0; j < 2; j++) {
                int cc = n0 + j * 16 + col;
                out[(size_t)row * DIM + cc] =
                    x[(size_t)row * DIM + cc] + acc[i][j][r] * inv;
            }
        }
}

extern "C" void kernel_launch(void* const* d_in, const int* in_sizes, int n_in,
                              void* d_out, int out_size, void* d_ws, size_t ws_size,
                              hipStream_t stream) {
    (void)in_sizes; (void)n_in; (void)out_size; (void)ws_size;
    const float* x      = (const float*)d_in[0];
    const float* vision = (const float*)d_in[1];
    const void*  mask   = d_in[2];
    const float* Wu     = (const float*)d_in[3];
    const float* bu     = (const float*)d_in[4];
    const float* Wk     = (const float*)d_in[5];
    const float* Wv     = (const float*)d_in[6];
    float* out = (float*)d_out;
    float* ws  = (float*)d_ws;
    int*   wsi = (int*)d_ws;

    k1<<<1600, 256, 0, stream>>>(vision, Wu, bu, x, Wk, Wv, mask, ws, wsi);
    g_attn<<<256, 256, 0, stream>>>(ws, wsi);
    g_out_mfma<<<256, 256, 0, stream>>>(x, ws, out);
}

// Round 12
// 149.070 us; speedup vs baseline: 1.2624x; 1.2624x over previous
//
#include <hip/hip_runtime.h>
#include <stdint.h>

#define B 4
#define T 256
#define V 1024
#define S 64
#define DIM 1024
#define CV 256

typedef __attribute__((ext_vector_type(8))) short bf16x8;
typedef __attribute__((ext_vector_type(4))) short s16x4;
typedef __attribute__((ext_vector_type(4))) float f32x4;

// ---- workspace layout, 4-byte word offsets; bf16 arrays counted in words. ----
// CORRECT sizes (R5-R10 had WkT/WvT/XB at half size -> overlapping regions).
enum : int {
    WKT_O  = 0,                     // [1024*1024] bf16 WkT [d][e]    = 524288 w
    WVT_O  = WKT_O + 524288,        // [1024*1024] bf16 WvT [d][e]    = 524288 w
    WUB_O  = WVT_O + 524288,        // [256*1024]  bf16 Wu            = 131072 w
    WKPB_O = WUB_O + 131072,        // [256*1024]  bf16 Wkp [cv][d]   = 131072 w
    WVPT_O = WKPB_O + 131072,       // [1024*256]  bf16 WvpT [d][cv]  = 131072 w
    XB_O   = WVPT_O + 131072,       // [1024*1024] bf16 x [bt][d]     = 524288 w
    VB_O   = XB_O + 524288,         // [4096*256]  bf16 vision        = 524288 w
    WB_O   = VB_O + 524288,         // [1024*256]  bf16 W [bt][cv]    = 131072 w
    RS_O   = WB_O + 131072,         // [1024] f32 per-token sum of p
    PIDX_O = RS_O + B*T,            // [B*T*S] int selected v
    BK_O   = PIDX_O + B*T*S,        // [DIM] f32 bu@Wk (g_prep blk 128)
    BV_O   = BK_O + DIM,            // [DIM] f32 bu@Wv (g_prep blk 129)
    BP_O   = BV_O + DIM,            // [2][16][1024] f32 bias partials
    WS_TOTAL = BP_O + 2*16*1024     // ~11 MB
};

__device__ __forceinline__ short f2bf(float f) {
    union { float f; unsigned u; } x; x.f = f;
    unsigned r = (x.u + 0x7FFF + ((x.u >> 16) & 1)) >> 16;
    return (short)r;
}
__device__ __forceinline__ float bf2f(short s) {
    union { unsigned u; float f; } x;
    x.u = ((unsigned)(unsigned short)s) << 16;
    return x.f;
}
__device__ __forceinline__ s16x4 cvt4(float4 f) {
    s16x4 o;
    o.x = f2bf(f.x); o.y = f2bf(f.y); o.z = f2bf(f.z); o.w = f2bf(f.w);
    return o;
}

// ================= stage 1: input conversion + mask compaction ================
// blocks [0,1024)    : vision f32 -> bf16
// blocks [1024,1280) : Wu f32 -> bf16
// blocks [1280,2304) : x f32 -> bf16
// blocks [2304,2816) : Wk/Wv transpose-convert -> bf16 [d][e] + bias partials
// blocks [2816,2880) : mask compaction (self-detecting encoding)
__global__ void stage1(const float* __restrict__ vision, const float* __restrict__ Wu,
                       const float* __restrict__ x, const float* __restrict__ Wk,
                       const float* __restrict__ Wv, const float* __restrict__ bu,
                       const void* __restrict__ maskp,
                       float* __restrict__ ws, int* __restrict__ wsi) {
    __shared__ short tlds[64 * 65];
    __shared__ float tred[4 * 64];
    __shared__ int mc_cnt[16][17];
    __shared__ int sa_flag, sb_flag;
    int blk = blockIdx.x;
    int tid = threadIdx.x;

    if (blk < 2304) {  // ---- straight f32 -> bf16 converts ----
        const float* src; short* dst; int idx;
        if (blk < 1024)      { src = vision; dst = (short*)(ws + VB_O);  idx = blk; }
        else if (blk < 1280) { src = Wu;     dst = (short*)(ws + WUB_O); idx = blk - 1024; }
        else                 { src = x;      dst = (short*)(ws + XB_O);  idx = blk - 1280; }
        int i = idx * 256 + tid;
        ((s16x4*)dst)[i] = cvt4(((const float4*)src)[i]);
        return;
    }
    if (blk < 2816) {  // ---- transpose-convert Wk/Wv + bias partials ----
        int tile = blk - 2304;
        int which = tile >> 8, t2 = tile & 255;
        int e0 = (t2 >> 4) * 64, d0 = (t2 & 15) * 64;
        const float* src = which ? Wv : Wk;
        short* dst = (short*)(ws + (which ? WVT_O : WKT_O));
        int j = tid & 63, i0 = tid >> 6;
        float pb = 0.f;
#pragma unroll
        for (int p = 0; p < 16; p++) {
            int i = p * 4 + i0;
            float v = src[(size_t)(e0 + i) * DIM + d0 + j];
            tlds[j * 65 + i] = f2bf(v);
            pb += bu[e0 + i] * v;
        }
        tred[i0 * 64 + j] = pb;
        __syncthreads();
#pragma unroll
        for (int p = 0; p < 16; p++) {
            int dd = p * 4 + i0;
            dst[(size_t)(d0 + dd) * DIM + e0 + j] = tlds[dd * 65 + j];
        }
        if (i0 == 0) {
            float s = tred[j] + tred[64 + j] + tred[128 + j] + tred[192 + j];
            ws[BP_O + (which * 16 + (e0 >> 6)) * 1024 + d0 + j] = s;
        }
        return;
    }
    // ---- mask compaction with block-local encoding detection ----
    {
        int a = 0, bfl = 0;
        const uchar4* m4 = (const uchar4*)maskp;
#pragma unroll
        for (int jj = 0; jj < 4; jj++) {
            uchar4 u = m4[tid * 4 + jj];
            if (u.y | u.z | u.w) a = 1;
            if (u.x == 0x3f || u.y == 0x3f || u.z == 0x3f || u.w == 0x3f) bfl = 1;
        }
        if (tid == 0) { sa_flag = 0; sb_flag = 0; }
        __syncthreads();
        if (a) sa_flag = 1;
        if (bfl) sb_flag = 1;
        __syncthreads();
    }
    bool byteMode = sa_flag && !sb_flag;
    int mb = blk - 2816;
    int b = mb >> 4, tg = mb & 15;
    int tl = tid & 15, c = tid >> 4;
    int t = tg * 16 + tl;
    int v0 = c * 64;
    unsigned long long bits = 0ull;
    if (byteMode) {
        const uint8_t* m = (const uint8_t*)maskp + (size_t)(b * V + v0) * T + t;
#pragma unroll 8
        for (int j = 0; j < 64; j++)
            if (m[(size_t)j * T] != 0) bits |= 1ull << j;
    } else {
        const int* m = (const int*)maskp + (size_t)(b * V + v0) * T + t;
#pragma unroll 8
        for (int j = 0; j < 64; j++)
            if (m[(size_t)j * T] != 0) bits |= 1ull << j;
    }
    mc_cnt[tl][c] = __popcll(bits);
    __syncthreads();
    int off = 0, total = 0;
#pragma unroll
    for (int cc = 0; cc < 16; cc++) {
        int cn = mc_cnt[tl][cc];
        if (cc < c) off += cn;
        total += cn;
    }
    int base = PIDX_O + (b * T + t) * S;
    while (bits) {
        int j = __ffsll(bits) - 1;
        bits &= bits - 1;
        if (off < S) wsi[base + off] = v0 + j;
        off++;
    }
    if (c == 15)
        for (int j = (total < S ? total : S); j < S; j++) wsi[base + j] = 0;
}

// ---- per-wave 32x32 MFMA tile: A[m][k] row-major, Bt[n][k] row-major ----
template<int K, int LDA, int LDB>
__device__ __forceinline__ void wave_mma(const short* __restrict__ A0,
                                         const short* __restrict__ B0,
                                         f32x4 acc[2][2]) {
    int lane = threadIdx.x & 63;
    int rw = lane & 15, q = lane >> 4;
    const short* ap0 = A0 + rw * LDA + q * 8;
    const short* ap1 = ap0 + 16 * LDA;
    const short* bp0 = B0 + rw * LDB + q * 8;
    const short* bp1 = bp0 + 16 * LDB;
#pragma unroll 4
    for (int kc = 0; kc < K; kc += 32) {
        bf16x8 a0 = *(const bf16x8*)(ap0 + kc);
        bf16x8 a1 = *(const bf16x8*)(ap1 + kc);
        bf16x8 b0 = *(const bf16x8*)(bp0 + kc);
        bf16x8 b1 = *(const bf16x8*)(bp1 + kc);
        acc[0][0] = __builtin_amdgcn_mfma_f32_16x16x32_bf16(a0, b0, acc[0][0], 0, 0, 0);
        acc[0][1] = __builtin_amdgcn_mfma_f32_16x16x32_bf16(a0, b1, acc[0][1], 0, 0, 0);
        acc[1][0] = __builtin_amdgcn_mfma_f32_16x16x32_bf16(a1, b0, acc[1][0], 0, 0, 0);
        acc[1][1] = __builtin_amdgcn_mfma_f32_16x16x32_bf16(a1, b1, acc[1][1], 0, 0, 0);
    }
}

// ---- g_prep: blocks 0..127 = 512 32x32 wave-tiles of Wkp = Wu@Wk (bf16
// ---- [cv][d]) / WvpT = (Wu@Wv)^T (bf16 [d][cv]); blocks 128/129 = bias reduce ----
__global__ void g_prep_mfma(float* __restrict__ ws) {
    if (blockIdx.x >= 128) {
        int which = blockIdx.x - 128;
#pragma unroll
        for (int cch = 0; cch < 4; cch++) {
            int d = cch * 256 + threadIdx.x;
            float s = 0.f;
#pragma unroll
            for (int g = 0; g < 16; g++)
                s += ws[BP_O + (which * 16 + g) * 1024 + d];
            ws[(which ? BV_O : BK_O) + d] = s;
        }
        return;
    }
    int w = blockIdx.x * 4 + (threadIdx.x >> 6);
    int which = w >> 8, rem = w & 255;
    int m0 = (rem >> 5) * 32, n0 = (rem & 31) * 32;  // m: cv(256), n: d(1024)
    const short* A = (const short*)(ws + WUB_O) + (size_t)m0 * DIM;
    const short* Bt = (const short*)(ws + (which ? WVT_O : WKT_O)) + (size_t)n0 * DIM;
    f32x4 acc[2][2] = {};
    wave_mma<DIM, DIM, DIM>(A, Bt, acc);
    int lane = threadIdx.x & 63, col = lane & 15, q = lane >> 4;
    if (which == 0) {
        short* o = (short*)(ws + WKPB_O);
#pragma unroll
        for (int i = 0; i < 2; i++)
#pragma unroll
            for (int j = 0; j < 2; j++)
#pragma unroll
                for (int r = 0; r < 4; r++)
                    o[(size_t)(m0 + i * 16 + q * 4 + r) * DIM + n0 + j * 16 + col] =
                        f2bf(acc[i][j][r]);
    } else {
        short* o = (short*)(ws + WVPT_O);
#pragma unroll
        for (int i = 0; i < 2; i++)
#pragma unroll
            for (int j = 0; j < 2; j++) {
                s16x4 v;
                v.x = f2bf(acc[i][j][0]); v.y = f2bf(acc[i][j][1]);
                v.z = f2bf(acc[i][j][2]); v.w = f2bf(acc[i][j][3]);
                *(s16x4*)&o[(size_t)(n0 + j * 16 + col) * CV + m0 + i * 16 + q * 4] = v;
            }
    }
}

// ---- g_attn: block = 4 bt. Phase 1: z[4][256] = xb @ Wkp^T cooperatively via
// ---- MFMA (B-frag = 4 xb rows, cols 4..15 wasted), LDS round-trip as bf16.
// ---- Phase 2 (wave = 1 bt): c0 = x.bk; scores = gathered VB rows . z (K=256);
// ---- exp; RS; W bf16 = sum p*vis_row. 256 blocks x 4 waves. ----
__global__ void g_attn(const float* __restrict__ x, float* __restrict__ ws,
                       int* __restrict__ wsi) {
    __shared__ short zs[4][256];       // bf16 z rows for the block's 4 bt
    __shared__ int s_idx[4][64];
    __shared__ float s_ps[4][64];
    int tid = threadIdx.x, lane = tid & 63, wv = tid >> 6;
    int bt0 = blockIdx.x * 4;
    int bt = bt0 + wv, b = bt >> 8;
    int rw = lane & 15, q = lane >> 4;
    s_idx[wv][lane] = wsi[PIDX_O + bt * S + lane];    // S == 64, wave-local

    // ---- phase 1: z tile. Wave wv covers cv chunk [wv*64, wv*64+64). ----
    {
        const short* xb = (const short*)(ws + XB_O);
        const short* wkp = (const short*)(ws + WKPB_O);
        const short* bp = xb + (size_t)(bt0 + rw) * DIM + q * 8;  // rows 4..15 junk (finite)
#pragma unroll
        for (int tt = 0; tt < 4; tt++) {
            int m0 = wv * 64 + tt * 16;
            const short* ap = wkp + (size_t)(m0 + rw) * DIM + q * 8;
            f32x4 a4 = {0.f, 0.f, 0.f, 0.f};
#pragma unroll 8
            for (int kc = 0; kc < DIM; kc += 32) {
                bf16x8 av = *(const bf16x8*)(ap + kc);
                bf16x8 bv = *(const bf16x8*)(bp + kc);
                a4 = __builtin_amdgcn_mfma_f32_16x16x32_bf16(av, bv, a4, 0, 0, 0);
            }
            int col = lane & 15;              // C col = bt-local (B-row index)
            if (col < 4) {                    // rows m = q*4+r -> cv local
                s16x4 v;
                v.x = f2bf(a4[0]); v.y = f2bf(a4[1]);
                v.z = f2bf(a4[2]); v.w = f2bf(a4[3]);
                *(s16x4*)&zs[col][m0 + q * 4] = v;
            }
        }
    }
    __syncthreads();

    // ---- phase 2: attention for this wave's bt ----
    // c0 = x[bt] . bk (f32 butterfly)
    float c0p = 0.f;
    const float4* xr = (const float4*)(x + (size_t)bt * DIM);
    const float4* bkr = (const float4*)(ws + BK_O);
#pragma unroll
    for (int j = 0; j < 4; j++) {
        float4 a = xr[lane + 64 * j], k4 = bkr[lane + 64 * j];
        c0p += a.x * k4.x + a.y * k4.y + a.z * k4.z + a.w * k4.w;
    }
    for (int o = 32; o > 0; o >>= 1) c0p += __shfl_xor(c0p, o);
    float c0 = c0p;
    // scores: A = 16 gathered bf16 vision rows, B = z broadcast into 16 cols
    const short* vb = (const short*)(ws + VB_O) + (size_t)b * V * CV;
    const short* zp = &zs[wv][q * 8];
    f32x4 acc[4] = {};
#pragma unroll
    for (int mt = 0; mt < 4; mt++) {
        const short* ap = vb + (size_t)s_idx[wv][mt * 16 + rw] * CV + q * 8;
        f32x4 a4 = {0.f, 0.f, 0.f, 0.f};
#pragma unroll
        for (int kc = 0; kc < CV; kc += 32) {
            bf16x8 av = *(const bf16x8*)(ap + kc);
            bf16x8 bv = *(const bf16x8*)(zp + kc);
            a4 = __builtin_amdgcn_mfma_f32_16x16x32_bf16(av, bv, a4, 0, 0, 0);
        }
        acc[mt] = a4;
    }
    if (rw == 0) {   // C rows = q*4+r; all 16 cols identical (z broadcast)
#pragma unroll
        for (int mt = 0; mt < 4; mt++)
#pragma unroll
            for (int r = 0; r < 4; r++)
                s_ps[wv][mt * 16 + q * 4 + r] = acc[mt][r];
    }
    float p = expf((s_ps[wv][lane] + c0) * 0.03125f);   // 1/sqrt(DIM)
    float rs = p;
    for (int o = 32; o > 0; o >>= 1) rs += __shfl_xor(rs, o);
    s_ps[wv][lane] = p;
    if (lane == 0) ws[RS_O + bt] = rs;
    // W accum from bf16 vision rows: lane covers cv = lane*4..+3
    float4 wa = {0.f, 0.f, 0.f, 0.f};
#pragma unroll 8
    for (int s = 0; s < S; s++) {
        float pv = s_ps[wv][s];
        s16x4 r4 = *(const s16x4*)(vb + (size_t)s_idx[wv][s] * CV + lane * 4);
        wa.x += pv * bf2f(r4.x); wa.y += pv * bf2f(r4.y);
        wa.z += pv * bf2f(r4.z); wa.w += pv * bf2f(r4.w);
    }
    s16x4 o;
    o.x = f2bf(wa.x); o.y = f2bf(wa.y); o.z = f2bf(wa.z); o.w = f2bf(wa.w);
    ((s16x4*)((short*)(ws + WB_O) + (size_t)bt * CV))[lane] = o;
}

// ---- g_out: out = x + (Wb @ WvpT^T + rs*bv)/denom; denom from RS (no atomics) ----
__global__ void g_out_mfma(const float* __restrict__ x, float* __restrict__ ws,
                           float* __restrict__ out) {
    int w = blockIdx.x * 4 + (threadIdx.x >> 6);
    int m0 = (w >> 5) * 32, n0 = (w & 31) * 32;    // m: bt(1024), n: d(1024)
    int lane = threadIdx.x & 63;
    int b = m0 >> 8;
    float4 r4 = *(const float4*)(ws + RS_O + b * 256 + lane * 4);
    float dn = r4.x + r4.y + r4.z + r4.w;
    for (int o = 32; o > 0; o >>= 1) dn += __shfl_xor(dn, o);
    float inv = 1.0f / dn;
    const short* A = (const short*)(ws + WB_O) + (size_t)m0 * CV;
    const short* Bt = (const short*)(ws + WVPT_O) + (size_t)n0 * CV;
    f32x4 acc[2][2] = {};
    wave_mma<CV, CV, CV>(A, Bt, acc);
    int col = lane & 15, q = lane >> 4;
#pragma unroll
    for (int i = 0; i < 2; i++)
#pragma unroll
        for (int r = 0; r < 4; r++) {
            int row = m0 + i * 16 + q * 4 + r;
            float rs = ws[RS_O + row];
#pragma unroll
            for (int j = 0; j < 2; j++) {
                int cc = n0 + j * 16 + col;
                out[(size_t)row * DIM + cc] =
                    x[(size_t)row * DIM + cc] +
                    (acc[i][j][r] + rs * ws[BV_O + cc]) * inv;
            }
        }
}

extern "C" void kernel_launch(void* const* d_in, const int* in_sizes, int n_in,
                              void* d_out, int out_size, void* d_ws, size_t ws_size,
                              hipStream_t stream) {
    (void)in_sizes; (void)n_in; (void)out_size; (void)ws_size;
    const float* x      = (const float*)d_in[0];
    const float* vision = (const float*)d_in[1];
    const void*  mask   = d_in[2];
    const float* Wu     = (const float*)d_in[3];
    const float* bu     = (const float*)d_in[4];
    const float* Wk     = (const float*)d_in[5];
    const float* Wv     = (const float*)d_in[6];
    float* out = (float*)d_out;
    float* ws  = (float*)d_ws;
    int*   wsi = (int*)d_ws;

    stage1<<<2880, 256, 0, stream>>>(vision, Wu, x, Wk, Wv, bu, mask, ws, wsi);
    g_prep_mfma<<<130, 256, 0, stream>>>(ws);
    g_attn<<<256, 256, 0, stream>>>(x, ws, wsi);
    g_out_mfma<<<256, 256, 0, stream>>>(x, ws, out);
}